// Round 6
// baseline (205.658 us; speedup 1.0000x reference)
//
#include <hip/hip_runtime.h>
#include <hip/hip_bf16.h>
#include <hip/hip_cooperative_groups.h>

namespace cg = cooperative_groups;

#define B_    512
#define F_    128
#define NTRIP 1024
#define MARGIN 1.0f
#define NBLK  32      // 512/16 pair-blocks per dim
#define NGRID 264     // grid: each block folds pair-blocks {bid, bid+264}
#define NG2   24      // stage-1 reduced slab count
#define GSZ   11      // slabs per stage-1 group (24*11 = 264)

// ws layout (float offsets)
#define OFF_M    0            // 128*512
#define OFF_G    65536        // 128
#define OFF_TL   65664        // 2 triplet partials
#define OFF_S    65680        // 128*128
#define OFF_PART 82064        // 264*16384 fp32
#define OFF_P2   (OFF_PART + NGRID * 16384)   // 24*16384 fp32

typedef __attribute__((ext_vector_type(8))) short bf16x8;
typedef __attribute__((ext_vector_type(4))) float f32x4;

#define LDS_ROW 20   // dwords per Dt row: 32 bf16 = 16 dwords, +4 pad (80 B)

__device__ inline unsigned int bf16r(float f) {   // RNE float->bf16 (f>=0, finite)
    unsigned int u = __float_as_uint(f);
    u += 0x7FFFu + ((u >> 16) & 1u);
    return u >> 16;
}

// ============ phase bodies (shared by coop kernel and fallback) ============

__device__ __forceinline__ void d_prep(const float* __restrict__ emb,
                                       const int* __restrict__ trip,
                                       float* __restrict__ m, float* __restrict__ g,
                                       float* __restrict__ tl,
                                       int bid, int t, float* sm) {
    if (bid < F_) {
        float* x   = sm;          // [512]
        float* red = sm + 512;    // [512]
        const int i = bid;
        x[t] = emb[t * F_ + i];
        __syncthreads();
        const float xa = x[t];
        float s0 = 0.f, s1 = 0.f, s2 = 0.f, s3 = 0.f;
        for (int b = 0; b < B_; b += 4) {
            s0 += fabsf(xa - x[b]);
            s1 += fabsf(xa - x[b + 1]);
            s2 += fabsf(xa - x[b + 2]);
            s3 += fabsf(xa - x[b + 3]);
        }
        float s = (s0 + s1) + (s2 + s3);
        m[i * B_ + t] = s * (1.f / B_);
        red[t] = s;
        __syncthreads();
        for (int sh = 256; sh > 0; sh >>= 1) {
            if (t < sh) red[t] += red[t + sh];
            __syncthreads();
        }
        if (t == 0) g[i] = red[0] * (1.f / ((float)B_ * (float)B_));
    } else if (bid < F_ + 2) {
        float* red = sm;
        const int tt = (bid - F_) * 512 + t;     // 0..1023
        int a = trip[3 * tt]     & (B_ - 1);
        int p = trip[3 * tt + 1] & (B_ - 1);
        int n = trip[3 * tt + 2] & (B_ - 1);
        const float4* ea = (const float4*)(emb + a * F_);
        const float4* ep = (const float4*)(emb + p * F_);
        const float4* en = (const float4*)(emb + n * F_);
        float ap = 0.f, an = 0.f;
        #pragma unroll 8
        for (int f4 = 0; f4 < F_ / 4; ++f4) {
            float4 va = ea[f4], vp = ep[f4], vn = en[f4];
            float d;
            d = va.x - vp.x; ap = fmaf(d, d, ap);
            d = va.y - vp.y; ap = fmaf(d, d, ap);
            d = va.z - vp.z; ap = fmaf(d, d, ap);
            d = va.w - vp.w; ap = fmaf(d, d, ap);
            d = va.x - vn.x; an = fmaf(d, d, an);
            d = va.y - vn.y; an = fmaf(d, d, an);
            d = va.z - vn.z; an = fmaf(d, d, an);
            d = va.w - vn.w; an = fmaf(d, d, an);
        }
        float l = fmaxf(ap - an + MARGIN, 0.f);
        red[t] = l;
        __syncthreads();
        for (int sh = 256; sh > 0; sh >>= 1) {
            if (t < sh) red[t] += red[t + sh];
            __syncthreads();
        }
        if (t == 0) tl[bid - F_] = red[0];
    }
}

__device__ __forceinline__ void d_pair(const float* __restrict__ emb,
                                       float* __restrict__ part,
                                       int bid, int t, unsigned int* dt) {
    const int lane = t & 63;
    const int w    = t >> 6;           // wave 0..7 -> T row-band
    const int i    = t & 127;          // feature (d-gen)
    const int quarter = t >> 7;        // 0..3
    const int halfq   = quarter >> 1;
    const int pbbase  = (quarter & 1) * 8;
    const int fr_row = lane & 15;
    const int fr_k4  = (lane >> 4) * 4;

    f32x4 acc[8];
    #pragma unroll
    for (int c = 0; c < 8; ++c) acc[c] = (f32x4)(0.f);

    for (int half = 0; half < 2; ++half) {
        const int L = bid + half * NGRID;       // pair-block id 0..527
        int ba = 0, rem = L;
        while (rem >= NBLK - ba) { rem -= NBLK - ba; ++ba; }
        const int bb = ba + rem;
        const bool diag = (ba == bb);

        float xb[8], xa[8];
        #pragma unroll
        for (int kk = 0; kk < 8; ++kk)
            xb[kk] = emb[(bb * 16 + pbbase + kk) * F_ + i];
        #pragma unroll
        for (int s = 0; s < 8; ++s)
            xa[s] = emb[(ba * 16 + s * 2 + halfq) * F_ + i];

        #pragma unroll 2
        for (int s = 0; s < 8; ++s) {
            const int buf = s & 1;
            const int pa  = s * 2 + halfq;
            unsigned int pk[4];
            #pragma unroll
            for (int q = 0; q < 4; ++q) {
                float d0 = fabsf(xa[s] - xb[2 * q]);
                float d1 = fabsf(xa[s] - xb[2 * q + 1]);
                if (diag && pa >= pbbase + 2 * q)     d0 = 0.f;
                if (diag && pa >= pbbase + 2 * q + 1) d1 = 0.f;
                pk[q] = bf16r(d0) | (bf16r(d1) << 16);
            }
            *reinterpret_cast<uint4*>(&dt[buf * (F_ * LDS_ROW) + i * LDS_ROW + quarter * 4]) =
                make_uint4(pk[0], pk[1], pk[2], pk[3]);
            __syncthreads();   // single barrier per step (dbuf covers WAR)

            const bf16x8 fA = *reinterpret_cast<const bf16x8*>(
                &dt[buf * (F_ * LDS_ROW) + (w * 16 + fr_row) * LDS_ROW + fr_k4]);
            #pragma unroll
            for (int c = 0; c < 8; ++c) {
                bf16x8 fB;
                if (c == w) fB = fA;
                else fB = *reinterpret_cast<const bf16x8*>(
                         &dt[buf * (F_ * LDS_ROW) + (c * 16 + fr_row) * LDS_ROW + fr_k4]);
                acc[c] = __builtin_amdgcn_mfma_f32_16x16x32_bf16(fA, fB, acc[c], 0, 0, 0);
            }
        }
    }

    float* dst = part + (size_t)bid * (F_ * F_);
    const int r0 = w * 16 + (lane >> 4) * 4;
    const int cj = lane & 15;
    #pragma unroll
    for (int c = 0; c < 8; ++c)
        #pragma unroll
        for (int r = 0; r < 4; ++r)
            dst[(r0 + r) * F_ + c * 16 + cj] = acc[c][r];
}

// task 0..383: gg = task>>4, seg = (task&15)*2 + (t>>8)
__device__ __forceinline__ void d_s1(const float* __restrict__ part,
                                     float* __restrict__ part2,
                                     int task, int t, float4* sh) {
    const int gg  = task >> 4;
    const int seg = (task & 15) * 2 + (t >> 8);
    const int l   = t & 255;
    const int c4  = l & 127;
    const int par = l >> 7;

    const float4* base = reinterpret_cast<const float4*>(part)
                       + (size_t)(gg * GSZ) * 4096 + seg * 128 + c4;
    float4 a0 = make_float4(0.f, 0.f, 0.f, 0.f);
    float4 a1 = a0;
    #pragma unroll
    for (int k = 0; k < 6; ++k) {
        const int s = par + 2 * k;
        if (s < GSZ) {
            float4 v = base[(size_t)s * 4096];
            if (k & 1) { a1.x += v.x; a1.y += v.y; a1.z += v.z; a1.w += v.w; }
            else       { a0.x += v.x; a0.y += v.y; a0.z += v.z; a0.w += v.w; }
        }
    }
    sh[t] = make_float4(a0.x + a1.x, a0.y + a1.y, a0.z + a1.z, a0.w + a1.w);
    __syncthreads();
    if (l < 128) {
        float4 u = sh[t], v = sh[t + 128];
        reinterpret_cast<float4*>(part2)[(size_t)gg * 4096 + seg * 128 + l] =
            make_float4(u.x + v.x, u.y + v.y, u.z + v.z, u.w + v.w);
    }
}

// task 0..255: i = task>>1, jq = (task&1)*2 + (t>>8)
__device__ __forceinline__ void d_s2(const float* __restrict__ part2,
                                     const float* __restrict__ m,
                                     const float* __restrict__ g,
                                     float* __restrict__ S,
                                     int task, int t, float* red) {
    const int i  = task >> 1;
    const int jq = (task & 1) * 2 + (t >> 8);
    const int l  = t & 255;
    const int jl = l & 31;
    const int j  = jq * 32 + jl;
    const int sl = l >> 5;             // 0..7

    float T = 0.f;
    #pragma unroll
    for (int k = 0; k < 3; ++k)
        T += part2[(size_t)(sl * 3 + k) * (F_ * F_) + i * F_ + j];

    float md = 0.f;
    const float* mi = m + i * B_;
    const float* mj = m + j * B_;
    #pragma unroll 4
    for (int a = sl * 64; a < sl * 64 + 64; ++a) md = fmaf(mi[a], mj[a], md);

    float s_local = 2.f * T * (1.f / ((float)B_ * (float)B_))
                  - (2.f / (float)B_) * md
                  + (sl == 0 ? g[i] * g[j] : 0.f);

    red[t] = s_local;
    __syncthreads();
    if (l < 128) red[t] += red[t + 128];
    __syncthreads();
    if (l < 64) red[t] += red[t + 64];
    __syncthreads();
    if (l < 32) S[i * F_ + jq * 32 + l] = red[t] + red[t + 32];
}

__device__ __forceinline__ void d_final(const float* __restrict__ S,
                                        const float* __restrict__ tl,
                                        float* __restrict__ out,
                                        int t, float* sm) {
    float* sq  = sm;          // [128]
    float* red = sm + F_;     // [512]
    if (t < F_) sq[t] = sqrtf(sqrtf(S[t * F_ + t]));
    __syncthreads();
    float sum = 0.f;
    for (int idx = t; idx < F_ * F_; idx += 512) {
        int ii = idx >> 7, jj = idx & 127;
        if (ii < jj) {
            float sij = fmaxf(S[idx], 0.f);
            sum += sqrtf(sij) / (sq[ii] * sq[jj]);
        }
    }
    red[t] = sum;
    __syncthreads();
    for (int sh = 256; sh > 0; sh >>= 1) {
        if (t < sh) red[t] += red[t + sh];
        __syncthreads();
    }
    if (t == 0)
        out[0] = red[0] * (1.f / 8128.f) + (tl[0] + tl[1]) * (1.f / (float)NTRIP);
}

// ============ cooperative all-in-one ============
__global__ __launch_bounds__(512, 4)
void k_all(const float* __restrict__ emb, const int* __restrict__ trip,
           float* __restrict__ ws, float* __restrict__ out) {
    __shared__ __align__(16) unsigned int smem[2 * F_ * LDS_ROW];   // 20.5 KB
    float* m     = ws + OFF_M;
    float* g     = ws + OFF_G;
    float* tl    = ws + OFF_TL;
    float* S     = ws + OFF_S;
    float* part  = ws + OFF_PART;
    float* part2 = ws + OFF_P2;

    cg::grid_group grid = cg::this_grid();
    const int bid = blockIdx.x;
    const int t   = threadIdx.x;

    if (bid < F_ + 2) d_prep(emb, trip, m, g, tl, bid, t, (float*)smem);
    grid.sync();

    d_pair(emb, part, bid, t, smem);
    grid.sync();

    for (int task = bid; task < 384; task += NGRID) {
        __syncthreads();                 // guard smem reuse across iterations
        d_s1(part, part2, task, t, (float4*)smem);
    }
    grid.sync();

    if (bid < 256) d_s2(part2, m, g, S, bid, t, (float*)smem);
    grid.sync();

    if (bid == 0) d_final(S, tl, out, t, (float*)smem);
}

// ============ fallback wrappers (separate launches) ============
__global__ __launch_bounds__(512) void k_prep5(const float* __restrict__ emb,
                                               const int* __restrict__ trip,
                                               float* __restrict__ m, float* __restrict__ g,
                                               float* __restrict__ tl) {
    __shared__ __align__(16) float sm[1024];
    d_prep(emb, trip, m, g, tl, blockIdx.x, threadIdx.x, sm);
}
__global__ __launch_bounds__(512) void k_pair5(const float* __restrict__ emb,
                                               float* __restrict__ part) {
    __shared__ __align__(16) unsigned int dt[2 * F_ * LDS_ROW];
    d_pair(emb, part, blockIdx.x, threadIdx.x, dt);
}
__global__ __launch_bounds__(512) void k_s1_5(const float* __restrict__ part,
                                              float* __restrict__ part2) {
    __shared__ __align__(16) float4 sh[512];
    d_s1(part, part2, blockIdx.x, threadIdx.x, sh);
}
__global__ __launch_bounds__(512) void k_s2_5(const float* __restrict__ part2,
                                              const float* __restrict__ m,
                                              const float* __restrict__ g,
                                              float* __restrict__ S) {
    __shared__ __align__(16) float red[512];
    d_s2(part2, m, g, S, blockIdx.x, threadIdx.x, red);
}
__global__ __launch_bounds__(512) void k_final5(const float* __restrict__ S,
                                                const float* __restrict__ tl,
                                                float* __restrict__ out) {
    __shared__ __align__(16) float sm[F_ + 512];
    d_final(S, tl, out, threadIdx.x, sm);
}

extern "C" void kernel_launch(void* const* d_in, const int* in_sizes, int n_in,
                              void* d_out, int out_size, void* d_ws, size_t ws_size,
                              hipStream_t stream) {
    const float* emb = (const float*)d_in[0];
    const int*   trp = (const int*)d_in[1];
    float* ws  = (float*)d_ws;
    float* out = (float*)d_out;

    void* args[] = {(void*)&emb, (void*)&trp, (void*)&ws, (void*)&out};
    hipError_t err = hipLaunchCooperativeKernel((const void*)k_all, dim3(NGRID),
                                                dim3(512), args, 0, stream);
    if (err != hipSuccess) {
        // fallback: same phases as separate kernels
        float* m     = ws + OFF_M;
        float* g     = ws + OFF_G;
        float* tl    = ws + OFF_TL;
        float* S     = ws + OFF_S;
        float* part  = ws + OFF_PART;
        float* part2 = ws + OFF_P2;
        k_prep5 <<<F_ + 2, 512, 0, stream>>>(emb, trp, m, g, tl);
        k_pair5 <<<NGRID, 512, 0, stream>>>(emb, part);
        k_s1_5  <<<384, 512, 0, stream>>>(part, part2);
        k_s2_5  <<<256, 512, 0, stream>>>(part2, m, g, S);
        k_final5<<<1, 512, 0, stream>>>(S, tl, out);
    }
}

// Round 7
// 88.365 us; speedup vs baseline: 2.3274x; 2.3274x over previous
//
#include <hip/hip_runtime.h>
#include <hip/hip_bf16.h>

#define B_    512
#define F_    128
#define NTRIP 1024
#define MARGIN 1.0f
#define NBLK  32      // 512/16 pair-blocks per dim
#define NGRID 264     // pair blocks: each folds pair-blocks {bid, bid+264}
#define NG2   24      // stage-1 reduced slab count
#define GSZ   11      // slabs per stage-1 group (24*11 = 264)

// ws layout (float offsets)
#define OFF_M    0                       // 128*512 fp32
#define OFF_G    65536                   // 128
#define OFF_TL   65664                   // 2 triplet partials
#define OFF_CNT  65672                   // ticket counter (int)
#define OFF_S    65680                   // 128*128 fp32
#define OFF_PART 82064                   // ushort[264*16384] = 264*8192 floats
#define OFF_P2   (82064 + NGRID * 8192)  // float[24*16384]

typedef __attribute__((ext_vector_type(8))) short bf16x8;
typedef __attribute__((ext_vector_type(4))) float f32x4;

#define LDS_ROW 20   // dwords per Dt row: 32 bf16 = 16 dwords, +4 pad (80 B)

__device__ inline unsigned int bf16r(float f) {   // RNE float->bf16 (f>=0, finite)
    unsigned int u = __float_as_uint(f);
    u += 0x7FFFu + ((u >> 16) & 1u);
    return u >> 16;
}

// ================= K1: pair GEMM (blocks 0..263) + prep (264..393) =========
__global__ __launch_bounds__(512)
void k1_pair_prep(const float* __restrict__ emb, const int* __restrict__ trip,
                  float* __restrict__ m, float* __restrict__ g,
                  float* __restrict__ tl, int* __restrict__ cnt,
                  unsigned short* __restrict__ part) {
    __shared__ __align__(16) unsigned int smem[2 * F_ * LDS_ROW];   // 20.5 KB
    const int bid = blockIdx.x;
    const int t   = threadIdx.x;

    if (bid < NGRID) {
        // ---------- pair GEMM via MFMA: T = D^T D over 32-pair K-steps ----
        unsigned int* dt = smem;
        const int lane = t & 63;
        const int w    = t >> 6;           // wave 0..7 -> T row-band
        const int i    = t & 127;          // feature (d-gen)
        const int quarter = t >> 7;        // 0..3
        const int halfq   = quarter >> 1;
        const int pbbase  = (quarter & 1) * 8;
        const int fr_row = lane & 15;
        const int fr_k4  = (lane >> 4) * 4;

        f32x4 acc[8];
        #pragma unroll
        for (int c = 0; c < 8; ++c) acc[c] = (f32x4)(0.f);

        for (int half = 0; half < 2; ++half) {
            const int L = bid + half * NGRID;       // pair-block id 0..527
            int ba = 0, rem = L;
            while (rem >= NBLK - ba) { rem -= NBLK - ba; ++ba; }
            const int bb = ba + rem;
            const bool diag = (ba == bb);

            float xb[8], xa[8];
            #pragma unroll
            for (int kk = 0; kk < 8; ++kk)
                xb[kk] = emb[(bb * 16 + pbbase + kk) * F_ + i];
            #pragma unroll
            for (int s = 0; s < 8; ++s)
                xa[s] = emb[(ba * 16 + s * 2 + halfq) * F_ + i];

            #pragma unroll 2
            for (int s = 0; s < 8; ++s) {
                const int buf = s & 1;
                const int pa  = s * 2 + halfq;
                unsigned int pk[4];
                #pragma unroll
                for (int q = 0; q < 4; ++q) {
                    float d0 = fabsf(xa[s] - xb[2 * q]);
                    float d1 = fabsf(xa[s] - xb[2 * q + 1]);
                    if (diag && pa >= pbbase + 2 * q)     d0 = 0.f;
                    if (diag && pa >= pbbase + 2 * q + 1) d1 = 0.f;
                    pk[q] = bf16r(d0) | (bf16r(d1) << 16);
                }
                *reinterpret_cast<uint4*>(&dt[buf * (F_ * LDS_ROW) + i * LDS_ROW + quarter * 4]) =
                    make_uint4(pk[0], pk[1], pk[2], pk[3]);
                __syncthreads();   // single barrier per step (dbuf covers WAR)

                const bf16x8 fA = *reinterpret_cast<const bf16x8*>(
                    &dt[buf * (F_ * LDS_ROW) + (w * 16 + fr_row) * LDS_ROW + fr_k4]);
                #pragma unroll
                for (int c = 0; c < 8; ++c) {
                    bf16x8 fB;
                    if (c == w) fB = fA;
                    else fB = *reinterpret_cast<const bf16x8*>(
                             &dt[buf * (F_ * LDS_ROW) + (c * 16 + fr_row) * LDS_ROW + fr_k4]);
                    acc[c] = __builtin_amdgcn_mfma_f32_16x16x32_bf16(fA, fB, acc[c], 0, 0, 0);
                }
            }
        }

        // epilogue -> bf16 partial slab (C layout: col=lane&15, row=(lane>>4)*4+r)
        unsigned short* dst = part + (size_t)bid * (F_ * F_);
        const int r0 = w * 16 + (lane >> 4) * 4;
        const int cj = lane & 15;
        #pragma unroll
        for (int c = 0; c < 8; ++c)
            #pragma unroll
            for (int r = 0; r < 4; ++r)
                dst[(r0 + r) * F_ + c * 16 + cj] = (unsigned short)bf16r(acc[c][r]);
    } else {
        // ---------- prep: m/g (prep-bid 0..127), triplet (128..129) -------
        const int pb = bid - NGRID;
        float* sm = (float*)smem;
        if (pb == 0 && t == 0) *cnt = 0;      // reset K3 ticket every call
        if (pb < F_) {
            float* x   = sm;          // [512]
            float* red = sm + 512;    // [512]
            const int i = pb;
            x[t] = emb[t * F_ + i];
            __syncthreads();
            const float xa = x[t];
            float s0 = 0.f, s1 = 0.f, s2 = 0.f, s3 = 0.f;
            for (int b = 0; b < B_; b += 4) {
                s0 += fabsf(xa - x[b]);
                s1 += fabsf(xa - x[b + 1]);
                s2 += fabsf(xa - x[b + 2]);
                s3 += fabsf(xa - x[b + 3]);
            }
            float s = (s0 + s1) + (s2 + s3);
            m[i * B_ + t] = s * (1.f / B_);
            red[t] = s;
            __syncthreads();
            for (int sh = 256; sh > 0; sh >>= 1) {
                if (t < sh) red[t] += red[t + sh];
                __syncthreads();
            }
            if (t == 0) g[i] = red[0] * (1.f / ((float)B_ * (float)B_));
        } else {
            float* red = sm;
            const int tt = (pb - F_) * 512 + t;     // 0..1023
            int a = trip[3 * tt]     & (B_ - 1);
            int p = trip[3 * tt + 1] & (B_ - 1);
            int n = trip[3 * tt + 2] & (B_ - 1);
            const float4* ea = (const float4*)(emb + a * F_);
            const float4* ep = (const float4*)(emb + p * F_);
            const float4* en = (const float4*)(emb + n * F_);
            float ap = 0.f, an = 0.f;
            #pragma unroll 8
            for (int f4 = 0; f4 < F_ / 4; ++f4) {
                float4 va = ea[f4], vp = ep[f4], vn = en[f4];
                float d;
                d = va.x - vp.x; ap = fmaf(d, d, ap);
                d = va.y - vp.y; ap = fmaf(d, d, ap);
                d = va.z - vp.z; ap = fmaf(d, d, ap);
                d = va.w - vp.w; ap = fmaf(d, d, ap);
                d = va.x - vn.x; an = fmaf(d, d, an);
                d = va.y - vn.y; an = fmaf(d, d, an);
                d = va.z - vn.z; an = fmaf(d, d, an);
                d = va.w - vn.w; an = fmaf(d, d, an);
            }
            float l = fmaxf(ap - an + MARGIN, 0.f);
            red[t] = l;
            __syncthreads();
            for (int sh = 256; sh > 0; sh >>= 1) {
                if (t < sh) red[t] += red[t + sh];
                __syncthreads();
            }
            if (t == 0) tl[pb - F_] = red[0];
        }
    }
}

// ============ K2: reduce 264 bf16 slabs -> 24 fp32 slabs ====================
// 96 blocks: gg = bid>>2 (group), chunk = bid&3; thread handles 8 elems.
__global__ __launch_bounds__(512)
void k2_s1(const unsigned short* __restrict__ part, float* __restrict__ part2) {
    const int gg = blockIdx.x >> 2;
    const int e0 = (blockIdx.x & 3) * 4096 + threadIdx.x * 8;   // elem offset

    float a[8];
    #pragma unroll
    for (int z = 0; z < 8; ++z) a[z] = 0.f;

    const uint4* base = reinterpret_cast<const uint4*>(part + (size_t)(gg * GSZ) * 16384 + e0);
    #pragma unroll
    for (int k = 0; k < GSZ; ++k) {
        uint4 v = base[(size_t)k * 2048];      // 16384 ushorts / 8 per uint4
        a[0] += __uint_as_float(v.x << 16);
        a[1] += __uint_as_float(v.x & 0xFFFF0000u);
        a[2] += __uint_as_float(v.y << 16);
        a[3] += __uint_as_float(v.y & 0xFFFF0000u);
        a[4] += __uint_as_float(v.z << 16);
        a[5] += __uint_as_float(v.z & 0xFFFF0000u);
        a[6] += __uint_as_float(v.w << 16);
        a[7] += __uint_as_float(v.w & 0xFFFF0000u);
    }
    float* dst = part2 + (size_t)gg * 16384 + e0;
    *reinterpret_cast<float4*>(dst)     = make_float4(a[0], a[1], a[2], a[3]);
    *reinterpret_cast<float4*>(dst + 4) = make_float4(a[4], a[5], a[6], a[7]);
}

// ============ K3: S2 + ticket-gated finalize ================================
__global__ __launch_bounds__(512)
void k3_s2_final(const float* __restrict__ part2, const float* __restrict__ m,
                 const float* __restrict__ g, const float* __restrict__ tl,
                 float* __restrict__ S, float* __restrict__ out,
                 int* __restrict__ cnt) {
    __shared__ __align__(16) float sm[F_ + 512];
    const int bid = blockIdx.x;
    const int t   = threadIdx.x;

    {   // ---- S2: S[i][j] for i = bid>>1, jq = (bid&1)*2 + (t>>8) ----
        float* red = sm;                   // [512]
        const int i  = bid >> 1;
        const int jq = (bid & 1) * 2 + (t >> 8);
        const int l  = t & 255;
        const int jl = l & 31;
        const int j  = jq * 32 + jl;
        const int sl = l >> 5;             // 0..7

        float T = 0.f;
        #pragma unroll
        for (int k = 0; k < 3; ++k)
            T += part2[(size_t)(sl * 3 + k) * (F_ * F_) + i * F_ + j];

        float md = 0.f;
        const float* mi = m + i * B_;
        const float* mj = m + j * B_;
        #pragma unroll 4
        for (int a = sl * 64; a < sl * 64 + 64; ++a) md = fmaf(mi[a], mj[a], md);

        float s_local = 2.f * T * (1.f / ((float)B_ * (float)B_))
                      - (2.f / (float)B_) * md
                      + (sl == 0 ? g[i] * g[j] : 0.f);

        red[t] = s_local;
        __syncthreads();
        if (l < 128) red[t] += red[t + 128];
        __syncthreads();
        if (l < 64) red[t] += red[t + 64];
        __syncthreads();
        if (l < 32) S[i * F_ + jq * 32 + l] = red[t] + red[t + 32];
    }

    // ---- ticket: last block finalizes (value-deterministic) ----
    __threadfence();
    __syncthreads();
    __shared__ int ticket;
    if (t == 0) ticket = atomicAdd(cnt, 1);
    __syncthreads();
    if (ticket != (int)gridDim.x - 1) return;
    __threadfence();

    float* sq  = sm;          // [128]
    float* red = sm + F_;     // [512]
    if (t < F_) sq[t] = sqrtf(sqrtf(S[t * F_ + t]));
    __syncthreads();
    float sum = 0.f;
    for (int idx = t; idx < F_ * F_; idx += 512) {
        int ii = idx >> 7, jj = idx & 127;
        if (ii < jj) {
            float sij = fmaxf(S[idx], 0.f);
            sum += sqrtf(sij) / (sq[ii] * sq[jj]);
        }
    }
    red[t] = sum;
    __syncthreads();
    for (int sh = 256; sh > 0; sh >>= 1) {
        if (t < sh) red[t] += red[t + sh];
        __syncthreads();
    }
    if (t == 0)
        out[0] = red[0] * (1.f / 8128.f) + (tl[0] + tl[1]) * (1.f / (float)NTRIP);
}

extern "C" void kernel_launch(void* const* d_in, const int* in_sizes, int n_in,
                              void* d_out, int out_size, void* d_ws, size_t ws_size,
                              hipStream_t stream) {
    const float* emb = (const float*)d_in[0];
    const int*   trp = (const int*)d_in[1];
    float* ws    = (float*)d_ws;
    float* m     = ws + OFF_M;
    float* g     = ws + OFF_G;
    float* tl    = ws + OFF_TL;
    int*   cnt   = (int*)(ws + OFF_CNT);
    float* S     = ws + OFF_S;
    unsigned short* part = (unsigned short*)(ws + OFF_PART);
    float* part2 = ws + OFF_P2;
    float* out   = (float*)d_out;

    k1_pair_prep<<<NGRID + F_ + 2, 512, 0, stream>>>(emb, trp, m, g, tl, cnt, part);
    k2_s1       <<<NG2 * 4, 512, 0, stream>>>(part, part2);
    k3_s2_final <<<256, 512, 0, stream>>>(part2, m, g, tl, S, out, cnt);
}

// Round 8
// 53.949 us; speedup vs baseline: 3.8121x; 1.6379x over previous
//
#include <hip/hip_runtime.h>
#include <hip/hip_bf16.h>

#define B_    512
#define F_    128
#define NTRIP 1024
#define MARGIN 1.0f
#define NBLK  32      // 512/16 pair-blocks per dim
#define NPB   528     // upper-tri pair-blocks
#define PREP  130     // prep blocks: 128 m/g + 2 triplet

// ws layout (float offsets)
#define OFF_M    0                 // m [128][512]
#define OFF_MT   65536             // mT [512][128]
#define OFF_G    131072            // g [128]
#define OFF_TL   131200            // tl [2]
#define OFF_S    131216            // S [128][128]
#define OFF_PART 147600            // ushort[528*16384] (17.3 MB)

typedef __attribute__((ext_vector_type(8))) short bf16x8;
typedef __attribute__((ext_vector_type(4))) float f32x4;

#define LDS_ROW 20   // dwords per 32-pair row: 16 + 4 pad (80 B) — 0-conflict

__device__ inline unsigned int bf16r(float f) {   // RNE float->bf16 (f>=0, finite)
    unsigned int u = __float_as_uint(f);
    u += 0x7FFFu + ((u >> 16) & 1u);
    return u >> 16;
}

// ===== K1: blocks 0..129 prep (m/g/mT/triplet); 130..657 pair GEMM =========
__global__ __launch_bounds__(512)
void k1_prep_pair(const float* __restrict__ emb, const int* __restrict__ trip,
                  float* __restrict__ m, float* __restrict__ mT,
                  float* __restrict__ g, float* __restrict__ tl,
                  unsigned short* __restrict__ part) {
    __shared__ __align__(16) unsigned int dt[4 * F_ * LDS_ROW];   // 40 KB
    const int bid = blockIdx.x;
    const int t   = threadIdx.x;

    if (bid < PREP) {
        float* sm = (float*)dt;
        if (bid < F_) {
            // ---- m/g for feature i ----
            float* x   = sm;          // [512]
            float* red = sm + 512;    // [512]
            const int i = bid;
            x[t] = emb[t * F_ + i];
            __syncthreads();
            const float xa = x[t];
            float s0 = 0.f, s1 = 0.f, s2 = 0.f, s3 = 0.f;
            for (int b = 0; b < B_; b += 4) {
                s0 += fabsf(xa - x[b]);
                s1 += fabsf(xa - x[b + 1]);
                s2 += fabsf(xa - x[b + 2]);
                s3 += fabsf(xa - x[b + 3]);
            }
            float s = (s0 + s1) + (s2 + s3);
            float mv = s * (1.f / B_);
            m[i * B_ + t]  = mv;
            mT[t * F_ + i] = mv;
            red[t] = s;
            __syncthreads();
            for (int sh = 256; sh > 0; sh >>= 1) {
                if (t < sh) red[t] += red[t + sh];
                __syncthreads();
            }
            if (t == 0) g[i] = red[0] * (1.f / ((float)B_ * (float)B_));
        } else {
            // ---- triplet partial ----
            float* red = sm;
            const int tt = (bid - F_) * 512 + t;     // 0..1023
            int a = trip[3 * tt]     & (B_ - 1);
            int p = trip[3 * tt + 1] & (B_ - 1);
            int n = trip[3 * tt + 2] & (B_ - 1);
            const float4* ea = (const float4*)(emb + a * F_);
            const float4* ep = (const float4*)(emb + p * F_);
            const float4* en = (const float4*)(emb + n * F_);
            float ap = 0.f, an = 0.f;
            #pragma unroll 8
            for (int f4 = 0; f4 < F_ / 4; ++f4) {
                float4 va = ea[f4], vp = ep[f4], vn = en[f4];
                float d;
                d = va.x - vp.x; ap = fmaf(d, d, ap);
                d = va.y - vp.y; ap = fmaf(d, d, ap);
                d = va.z - vp.z; ap = fmaf(d, d, ap);
                d = va.w - vp.w; ap = fmaf(d, d, ap);
                d = va.x - vn.x; an = fmaf(d, d, an);
                d = va.y - vn.y; an = fmaf(d, d, an);
                d = va.z - vn.z; an = fmaf(d, d, an);
                d = va.w - vn.w; an = fmaf(d, d, an);
            }
            float l = fmaxf(ap - an + MARGIN, 0.f);
            red[t] = l;
            __syncthreads();
            for (int sh = 256; sh > 0; sh >>= 1) {
                if (t < sh) red[t] += red[t + sh];
                __syncthreads();
            }
            if (t == 0) tl[bid - F_] = red[0];
        }
        return;
    }

    // ---------------- pair GEMM: 2 phases, 3 barriers total ----------------
    const int pb = bid - PREP;          // pair-block id 0..527
    int ba = 0, rem = pb;
    while (rem >= NBLK - ba) { rem -= NBLK - ba; ++ba; }
    const int bb = ba + rem;
    const bool diag = (ba == bb);

    const int lane = t & 63;
    const int w    = t >> 6;
    const int wr   = w >> 1;          // 0..3: row-groups {2wr, 2wr+1}
    const int wc   = w & 1;           // 0..1: col-groups {4wc .. 4wc+3}
    const int i    = t & 127;         // feature (d-gen)
    const int pg   = t >> 7;          // 0..3: chunk / a-subrange
    const int fr_row = lane & 15;
    const int fr_k4  = (lane >> 4) * 4;

    f32x4 acc[2][4];
    #pragma unroll
    for (int q = 0; q < 2; ++q)
        #pragma unroll
        for (int c = 0; c < 4; ++c) acc[q][c] = (f32x4)(0.f);

    float xb[16];
    #pragma unroll
    for (int b = 0; b < 16; ++b) xb[b] = emb[(bb * 16 + b) * F_ + i];

    #pragma unroll
    for (int h = 0; h < 2; ++h) {
        const float xa0 = emb[(ba * 16 + h * 8 + pg * 2 + 0) * F_ + i];
        const float xa1 = emb[(ba * 16 + h * 8 + pg * 2 + 1) * F_ + i];
        if (h) __syncthreads();           // phase-0 reads done before restage
        #pragma unroll
        for (int ar2 = 0; ar2 < 2; ++ar2) {
            const float xa = ar2 ? xa1 : xa0;
            const int pa = h * 8 + pg * 2 + ar2;
            unsigned int pk[8];
            #pragma unroll
            for (int q = 0; q < 8; ++q) {
                float d0 = fabsf(xa - xb[2 * q]);
                float d1 = fabsf(xa - xb[2 * q + 1]);
                if (diag && pa >= 2 * q)     d0 = 0.f;
                if (diag && pa >= 2 * q + 1) d1 = 0.f;
                pk[q] = bf16r(d0) | (bf16r(d1) << 16);
            }
            unsigned int* dst = &dt[pg * (F_ * LDS_ROW) + i * LDS_ROW + ar2 * 8];
            *reinterpret_cast<uint4*>(dst)     = make_uint4(pk[0], pk[1], pk[2], pk[3]);
            *reinterpret_cast<uint4*>(dst + 4) = make_uint4(pk[4], pk[5], pk[6], pk[7]);
        }
        __syncthreads();
        #pragma unroll
        for (int c = 0; c < 4; ++c) {     // K-chunks of 32 pairs
            const unsigned int* base = &dt[c * (F_ * LDS_ROW)];
            const bf16x8 fA0 = *reinterpret_cast<const bf16x8*>(
                &base[((wr * 2 + 0) * 16 + fr_row) * LDS_ROW + fr_k4]);
            const bf16x8 fA1 = *reinterpret_cast<const bf16x8*>(
                &base[((wr * 2 + 1) * 16 + fr_row) * LDS_ROW + fr_k4]);
            #pragma unroll
            for (int cg = 0; cg < 4; ++cg) {
                const bf16x8 fB = *reinterpret_cast<const bf16x8*>(
                    &base[((wc * 4 + cg) * 16 + fr_row) * LDS_ROW + fr_k4]);
                acc[0][cg] = __builtin_amdgcn_mfma_f32_16x16x32_bf16(fA0, fB, acc[0][cg], 0, 0, 0);
                acc[1][cg] = __builtin_amdgcn_mfma_f32_16x16x32_bf16(fA1, fB, acc[1][cg], 0, 0, 0);
            }
        }
    }

    // epilogue -> bf16 slab; C layout: col=lane&15, row=(lane>>4)*4+reg
    unsigned short* dstp = part + (size_t)pb * (F_ * F_);
    const int cj = lane & 15;
    const int rsub = (lane >> 4) * 4;
    #pragma unroll
    for (int q = 0; q < 2; ++q)
        #pragma unroll
        for (int cg = 0; cg < 4; ++cg)
            #pragma unroll
            for (int r = 0; r < 4; ++r)
                dstp[((wr * 2 + q) * 16 + rsub + r) * F_ + (wc * 4 + cg) * 16 + cj] =
                    (unsigned short)bf16r(acc[q][cg][r]);
}

// ===== K2: block i -> full S row i (slab reduce + corrections) ==============
__global__ __launch_bounds__(512)
void k2_srow(const unsigned short* __restrict__ part, const float* __restrict__ m,
             const float* __restrict__ mT, const float* __restrict__ g,
             float* __restrict__ S) {
    __shared__ float shT[8][F_];      // 4 KB
    __shared__ float smi[B_];         // 2 KB
    __shared__ float shM[4][F_];      // 2 KB
    const int i = blockIdx.x;
    const int t = threadIdx.x;

    // ---- T[j] over 528 slabs: coalesced dword loads, 8 slices x 66 ----
    const int dw = t & 63;            // dword within row i (2 j's per dword)
    const int sl = t >> 6;            // 0..7
    const unsigned int* src = reinterpret_cast<const unsigned int*>(part) + i * 64 + dw;
    float tlo = 0.f, thi = 0.f;
    #pragma unroll 11
    for (int s = sl * 66; s < sl * 66 + 66; ++s) {
        unsigned int v = src[(size_t)s * 8192];
        tlo += __uint_as_float(v << 16);
        thi += __uint_as_float(v & 0xFFFF0000u);
    }
    shT[sl][dw * 2]     = tlo;
    shT[sl][dw * 2 + 1] = thi;
    smi[t] = m[i * B_ + t];
    __syncthreads();

    // ---- md[j] = <m_i, m_j> : 4 slices of 128 over a, mT coalesced ----
    const int j  = t & 127;
    const int q4 = t >> 7;            // 0..3
    float md = 0.f;
    const float* mta = mT + (q4 * 128) * F_ + j;
    const float* mia = smi + q4 * 128;
    #pragma unroll 8
    for (int a = 0; a < 128; ++a) md = fmaf(mia[a], mta[(size_t)a * F_], md);
    shM[q4][j] = md;
    __syncthreads();

    if (t < F_) {
        float T = 0.f;
        #pragma unroll
        for (int s = 0; s < 8; ++s) T += shT[s][t];
        float mdj = (shM[0][t] + shM[1][t]) + (shM[2][t] + shM[3][t]);
        S[i * F_ + t] = 2.f * T * (1.f / ((float)B_ * (float)B_))
                      - (2.f / (float)B_) * mdj
                      + g[i] * g[t];
    }
}

// ===== K3: finalize =========================================================
__global__ __launch_bounds__(512)
void k3_final(const float* __restrict__ S, const float* __restrict__ tl,
              float* __restrict__ out) {
    __shared__ float sq[F_];
    __shared__ float red[512];
    const int t = threadIdx.x;
    if (t < F_) sq[t] = sqrtf(sqrtf(S[t * F_ + t]));
    __syncthreads();
    float sum = 0.f;
    for (int idx = t; idx < F_ * F_; idx += 512) {
        int ii = idx >> 7, jj = idx & 127;
        if (ii < jj) {
            float sij = fmaxf(S[idx], 0.f);
            sum += sqrtf(sij) / (sq[ii] * sq[jj]);
        }
    }
    red[t] = sum;
    __syncthreads();
    for (int sh = 256; sh > 0; sh >>= 1) {
        if (t < sh) red[t] += red[t + sh];
        __syncthreads();
    }
    if (t == 0)
        out[0] = red[0] * (1.f / 8128.f) + (tl[0] + tl[1]) * (1.f / (float)NTRIP);
}

extern "C" void kernel_launch(void* const* d_in, const int* in_sizes, int n_in,
                              void* d_out, int out_size, void* d_ws, size_t ws_size,
                              hipStream_t stream) {
    const float* emb = (const float*)d_in[0];
    const int*   trp = (const int*)d_in[1];
    float* ws  = (float*)d_ws;
    float* m   = ws + OFF_M;
    float* mT  = ws + OFF_MT;
    float* g   = ws + OFF_G;
    float* tl  = ws + OFF_TL;
    float* S   = ws + OFF_S;
    unsigned short* part = (unsigned short*)(ws + OFF_PART);
    float* out = (float*)d_out;

    k1_prep_pair<<<PREP + NPB, 512, 0, stream>>>(emb, trp, m, mT, g, tl, part);
    k2_srow     <<<F_, 512, 0, stream>>>(part, m, mT, g, S);
    k3_final    <<<1, 512, 0, stream>>>(S, tl, out);
}

// Round 9
// 42.407 us; speedup vs baseline: 4.8496x; 1.2722x over previous
//
#include <hip/hip_runtime.h>
#include <hip/hip_bf16.h>

#define B_    512
#define F_    128
#define NTRIP 1024
#define MARGIN 1.0f
#define NBLK  32      // 512/16 pair-blocks per dim
#define NPB   528     // upper-tri pair-blocks
#define PREP  130     // prep blocks: 128 m/g + 2 triplet

// ws layout (float offsets)
#define OFF_M    0                 // m  [128][512]
#define OFF_MT   65536             // mT [512][128]
#define OFF_G    131072            // g  [128]
#define OFF_TL   131200            // tl [2]
#define OFF_SQ   131216            // sq [128] = sqrt(sqrt(S_ii))
#define OFF_PART 147600            // ushort[528*16384] (17.3 MB)

typedef __attribute__((ext_vector_type(8))) short bf16x8;
typedef __attribute__((ext_vector_type(4))) float f32x4;

#define LDS_ROW 20   // dwords per 32-pair row: 16 + 4 pad (80 B) — 0-conflict

__device__ inline unsigned int bf16r(float f) {   // RNE float->bf16 (f>=0, finite)
    unsigned int u = __float_as_uint(f);
    u += 0x7FFFu + ((u >> 16) & 1u);
    return u >> 16;
}

// ===== K1: blocks 0..129 prep (m/mT/g/sq/triplet); 130..657 pair GEMM ======
__global__ __launch_bounds__(512)
void k1_prep_pair(const float* __restrict__ emb, const int* __restrict__ trip,
                  float* __restrict__ m, float* __restrict__ mT,
                  float* __restrict__ g, float* __restrict__ tl,
                  float* __restrict__ sq, float* __restrict__ out,
                  unsigned short* __restrict__ part) {
    __shared__ __align__(16) unsigned int dt[4 * F_ * LDS_ROW];   // 40 KB
    const int bid = blockIdx.x;
    const int t   = threadIdx.x;

    if (bid < PREP) {
        if (bid < F_) {
            // ---- m/g/sq for feature i ----
            float*  x    = (float*)dt;                    // [512]
            float4* red4 = (float4*)((float*)dt + 512);   // [512] (8 KB)
            const int i = bid;
            if (i == 0 && t == 0) out[0] = 0.f;           // reset accumulator
            x[t] = emb[t * F_ + i];
            __syncthreads();
            const float xa = x[t];
            float s0 = 0.f, s1 = 0.f, s2 = 0.f, s3 = 0.f;
            for (int b = 0; b < B_; b += 4) {
                s0 += fabsf(xa - x[b]);
                s1 += fabsf(xa - x[b + 1]);
                s2 += fabsf(xa - x[b + 2]);
                s3 += fabsf(xa - x[b + 3]);
            }
            float s = (s0 + s1) + (s2 + s3);
            float mv = s * (1.f / B_);
            m[i * B_ + t]  = mv;
            mT[t * F_ + i] = mv;
            red4[t] = make_float4(s, xa, xa * xa, mv * mv);
            __syncthreads();
            for (int sh = 256; sh > 0; sh >>= 1) {
                if (t < sh) {
                    float4 a = red4[t], b = red4[t + sh];
                    red4[t] = make_float4(a.x + b.x, a.y + b.y, a.z + b.z, a.w + b.w);
                }
                __syncthreads();
            }
            if (t == 0) {
                float4 r = red4[0];
                const float Bf = (float)B_;
                float gi = r.x * (1.f / (Bf * Bf));
                g[i] = gi;
                float DD  = 2.f * Bf * r.z - 2.f * r.y * r.y;   // <D_i, D_i>
                float Sii = DD * (1.f / (Bf * Bf)) - (2.f / Bf) * r.w + gi * gi;
                sq[i] = sqrtf(sqrtf(fmaxf(Sii, 0.f)));
            }
        } else {
            // ---- triplet partial ----
            float* red = (float*)dt;
            const int tt = (bid - F_) * 512 + t;     // 0..1023
            int a = trip[3 * tt]     & (B_ - 1);
            int p = trip[3 * tt + 1] & (B_ - 1);
            int n = trip[3 * tt + 2] & (B_ - 1);
            const float4* ea = (const float4*)(emb + a * F_);
            const float4* ep = (const float4*)(emb + p * F_);
            const float4* en = (const float4*)(emb + n * F_);
            float ap = 0.f, an = 0.f;
            #pragma unroll 8
            for (int f4 = 0; f4 < F_ / 4; ++f4) {
                float4 va = ea[f4], vp = ep[f4], vn = en[f4];
                float d;
                d = va.x - vp.x; ap = fmaf(d, d, ap);
                d = va.y - vp.y; ap = fmaf(d, d, ap);
                d = va.z - vp.z; ap = fmaf(d, d, ap);
                d = va.w - vp.w; ap = fmaf(d, d, ap);
                d = va.x - vn.x; an = fmaf(d, d, an);
                d = va.y - vn.y; an = fmaf(d, d, an);
                d = va.z - vn.z; an = fmaf(d, d, an);
                d = va.w - vn.w; an = fmaf(d, d, an);
            }
            float l = fmaxf(ap - an + MARGIN, 0.f);
            red[t] = l;
            __syncthreads();
            for (int sh = 256; sh > 0; sh >>= 1) {
                if (t < sh) red[t] += red[t + sh];
                __syncthreads();
            }
            if (t == 0) tl[bid - F_] = red[0];
        }
        return;
    }

    // ---------------- pair GEMM: 2 phases, 3 barriers total ----------------
    const int pb = bid - PREP;          // pair-block id 0..527
    int ba = 0, rem = pb;
    while (rem >= NBLK - ba) { rem -= NBLK - ba; ++ba; }
    const int bb = ba + rem;
    const bool diag = (ba == bb);

    const int lane = t & 63;
    const int w    = t >> 6;
    const int wr   = w >> 1;          // 0..3: row-groups {2wr, 2wr+1}
    const int wc   = w & 1;           // 0..1: col-groups {4wc .. 4wc+3}
    const int i    = t & 127;         // feature (d-gen)
    const int pg   = t >> 7;          // 0..3: chunk / a-subrange
    const int fr_row = lane & 15;
    const int fr_k4  = (lane >> 4) * 4;

    f32x4 acc[2][4];
    #pragma unroll
    for (int q = 0; q < 2; ++q)
        #pragma unroll
        for (int c = 0; c < 4; ++c) acc[q][c] = (f32x4)(0.f);

    float xb[16];
    #pragma unroll
    for (int b = 0; b < 16; ++b) xb[b] = emb[(bb * 16 + b) * F_ + i];

    #pragma unroll
    for (int h = 0; h < 2; ++h) {
        const float xa0 = emb[(ba * 16 + h * 8 + pg * 2 + 0) * F_ + i];
        const float xa1 = emb[(ba * 16 + h * 8 + pg * 2 + 1) * F_ + i];
        if (h) __syncthreads();           // phase-0 reads done before restage
        #pragma unroll
        for (int ar2 = 0; ar2 < 2; ++ar2) {
            const float xa = ar2 ? xa1 : xa0;
            const int pa = h * 8 + pg * 2 + ar2;
            unsigned int pk[8];
            #pragma unroll
            for (int q = 0; q < 8; ++q) {
                float d0 = fabsf(xa - xb[2 * q]);
                float d1 = fabsf(xa - xb[2 * q + 1]);
                if (diag && pa >= 2 * q)     d0 = 0.f;
                if (diag && pa >= 2 * q + 1) d1 = 0.f;
                pk[q] = bf16r(d0) | (bf16r(d1) << 16);
            }
            unsigned int* dst = &dt[pg * (F_ * LDS_ROW) + i * LDS_ROW + ar2 * 8];
            *reinterpret_cast<uint4*>(dst)     = make_uint4(pk[0], pk[1], pk[2], pk[3]);
            *reinterpret_cast<uint4*>(dst + 4) = make_uint4(pk[4], pk[5], pk[6], pk[7]);
        }
        __syncthreads();
        #pragma unroll
        for (int c = 0; c < 4; ++c) {     // K-chunks of 32 pairs
            const unsigned int* base = &dt[c * (F_ * LDS_ROW)];
            const bf16x8 fA0 = *reinterpret_cast<const bf16x8*>(
                &base[((wr * 2 + 0) * 16 + fr_row) * LDS_ROW + fr_k4]);
            const bf16x8 fA1 = *reinterpret_cast<const bf16x8*>(
                &base[((wr * 2 + 1) * 16 + fr_row) * LDS_ROW + fr_k4]);
            #pragma unroll
            for (int cg = 0; cg < 4; ++cg) {
                const bf16x8 fB = *reinterpret_cast<const bf16x8*>(
                    &base[((wc * 4 + cg) * 16 + fr_row) * LDS_ROW + fr_k4]);
                acc[0][cg] = __builtin_amdgcn_mfma_f32_16x16x32_bf16(fA0, fB, acc[0][cg], 0, 0, 0);
                acc[1][cg] = __builtin_amdgcn_mfma_f32_16x16x32_bf16(fA1, fB, acc[1][cg], 0, 0, 0);
            }
        }
    }

    // epilogue -> bf16 slab; C layout: col=lane&15, row=(lane>>4)*4+reg
    unsigned short* dstp = part + (size_t)pb * (F_ * F_);
    const int cj = lane & 15;
    const int rsub = (lane >> 4) * 4;
    #pragma unroll
    for (int q = 0; q < 2; ++q)
        #pragma unroll
        for (int cg = 0; cg < 4; ++cg)
            #pragma unroll
            for (int r = 0; r < 4; ++r)
                dstp[((wr * 2 + q) * 16 + rsub + r) * F_ + (wc * 4 + cg) * 16 + cj] =
                    (unsigned short)bf16r(acc[q][cg][r]);
}

// ===== K2: 256 blocks; block -> half S-row + corr partial -> atomicAdd =====
// i = bid>>1, jh = bid&1 (j in [jh*64, jh*64+64))
__global__ __launch_bounds__(512)
void k2_srow_final(const unsigned short* __restrict__ part,
                   const float* __restrict__ m, const float* __restrict__ mT,
                   const float* __restrict__ g, const float* __restrict__ sq,
                   const float* __restrict__ tl, float* __restrict__ out) {
    __shared__ float shT[16][64];     // 4 KB: T slices
    __shared__ float shM[8][64];      // 2 KB: md slices
    __shared__ float smi[B_];         // 2 KB: m row i
    __shared__ float red[64];
    const int bid = blockIdx.x;
    const int i   = bid >> 1;
    const int jh  = bid & 1;
    const int t   = threadIdx.x;

    // ---- T[j] over 528 slabs: 16 slices x 33, 128 B coalesced chunks ----
    const int dw = t & 31;            // dword within half-row (2 j's per dword)
    const int sl = t >> 5;            // 0..15
    const unsigned int* src = reinterpret_cast<const unsigned int*>(part)
                            + i * 64 + jh * 32 + dw;
    float tlo = 0.f, thi = 0.f;
    #pragma unroll 11
    for (int s = sl * 33; s < sl * 33 + 33; ++s) {
        unsigned int v = src[(size_t)s * 8192];
        tlo += __uint_as_float(v << 16);
        thi += __uint_as_float(v & 0xFFFF0000u);
    }
    shT[sl][dw * 2]     = tlo;
    shT[sl][dw * 2 + 1] = thi;
    smi[t] = m[i * B_ + t];
    __syncthreads();

    // ---- md[j] = <m_i, m_j>: 8 slices of 64 a's, mT coalesced ----
    const int jl = t & 63;
    const int j  = jh * 64 + jl;
    const int q8 = t >> 6;            // 0..7
    float md = 0.f;
    const float* mta = mT + (size_t)(q8 * 64) * F_ + j;
    const float* mia = smi + q8 * 64;
    #pragma unroll 8
    for (int a = 0; a < 64; ++a) md = fmaf(mia[a], mta[(size_t)a * F_], md);
    shM[q8][jl] = md;
    __syncthreads();

    if (t < 64) {
        float T = 0.f;
        #pragma unroll
        for (int s = 0; s < 16; ++s) T += shT[s][t];
        float mdj = 0.f;
        #pragma unroll
        for (int s = 0; s < 8; ++s) mdj += shM[s][t];
        const int jj = jh * 64 + t;
        float Sij = 2.f * T * (1.f / ((float)B_ * (float)B_))
                  - (2.f / (float)B_) * mdj
                  + g[i] * g[jj];
        float c = 0.f;
        if (jj > i) c = sqrtf(fmaxf(Sij, 0.f)) / (sq[i] * sq[jj]);
        red[t] = c;
    }
    __syncthreads();
    for (int sh = 32; sh > 0; sh >>= 1) {
        if (t < sh) red[t] += red[t + sh];
        __syncthreads();
    }
    if (t == 0) {
        float v = red[0] * (1.f / 8128.f);
        if (bid == 0) v += (tl[0] + tl[1]) * (1.f / (float)NTRIP);
        atomicAdd(out, v);
    }
}

extern "C" void kernel_launch(void* const* d_in, const int* in_sizes, int n_in,
                              void* d_out, int out_size, void* d_ws, size_t ws_size,
                              hipStream_t stream) {
    const float* emb = (const float*)d_in[0];
    const int*   trp = (const int*)d_in[1];
    float* ws  = (float*)d_ws;
    float* m   = ws + OFF_M;
    float* mT  = ws + OFF_MT;
    float* g   = ws + OFF_G;
    float* tl  = ws + OFF_TL;
    float* sq  = ws + OFF_SQ;
    unsigned short* part = (unsigned short*)(ws + OFF_PART);
    float* out = (float*)d_out;

    k1_prep_pair  <<<PREP + NPB, 512, 0, stream>>>(emb, trp, m, mT, g, tl, sq, out, part);
    k2_srow_final <<<256, 512, 0, stream>>>(part, m, mT, g, sq, tl, out);
}